// Round 5
// baseline (174.841 us; speedup 1.0000x reference)
//
#include <hip/hip_runtime.h>
#include <cstdint>
#include <cstddef>

typedef __bf16 bf16x8 __attribute__((ext_vector_type(8)));
typedef float  f32x4  __attribute__((ext_vector_type(4)));
typedef float  f32x16 __attribute__((ext_vector_type(16)));
typedef int    i32x4  __attribute__((ext_vector_type(4)));

#define QMAX 7.0f
#define SCALE_MIN 2e-16f

#define BAR()     asm volatile("s_barrier" ::: "memory")
#define WAITVM(N) asm volatile("s_waitcnt vmcnt(" #N ")" ::: "memory")

// ---------------------------------------------------------------------------
// Kernel 1: per-output-channel fake-quant of w [256,256,3,3] -> bf16 wq[tap][o][c]
// ---------------------------------------------------------------------------
__global__ __launch_bounds__(256) void quant_w_kernel(const float* __restrict__ w,
                                                      __bf16* __restrict__ wq) {
    const int o = blockIdx.x;
    const int t = threadIdx.x;
    const float* wo = w + (size_t)o * 2304;

    float vals[9];
    float m = 0.f;
    #pragma unroll
    for (int i = 0; i < 9; ++i) {
        float v = wo[t + i * 256];
        vals[i] = v;
        m = fmaxf(m, fabsf(v));
    }
    #pragma unroll
    for (int off = 32; off >= 1; off >>= 1) m = fmaxf(m, __shfl_down(m, off));
    __shared__ float red[4];
    __shared__ float s_scale;
    if ((t & 63) == 0) red[t >> 6] = m;
    __syncthreads();
    if (t == 0) {
        float am = fmaxf(fmaxf(red[0], red[1]), fmaxf(red[2], red[3]));
        s_scale = fmaxf(am / QMAX, SCALE_MIN);
    }
    __syncthreads();
    const float scale = s_scale;

    #pragma unroll
    for (int i = 0; i < 9; ++i) {
        int idx = t + i * 256;           // = c*9 + tap
        int c = idx / 9;
        int tap = idx - c * 9;
        float q = rintf(vals[i] / scale);          // round-half-even, matches jnp.round
        q = fminf(QMAX, fmaxf(-QMAX, q));
        wq[(size_t)tap * 65536 + (size_t)o * 256 + c] = (__bf16)(q * scale);
    }
}

// ---------------------------------------------------------------------------
// Kernel 2: x NCHW fp32 [32,256,56,56] -> padded NHWC bf16 [32][58][58][256]
// ---------------------------------------------------------------------------
__global__ __launch_bounds__(256) void convert_x_kernel(const float* __restrict__ x,
                                                        __bf16* __restrict__ xpad) {
    __shared__ float tile[32][33];
    const int n  = blockIdx.z;
    const int c0 = blockIdx.y * 32;
    const int p0 = blockIdx.x * 32;
    const int tx = threadIdx.x & 31;
    const int ty = threadIdx.x >> 5;

    #pragma unroll
    for (int r = 0; r < 4; ++r) {
        int c = c0 + ty + r * 8;
        tile[ty + r * 8][tx] = x[((size_t)(n * 256 + c)) * 3136 + p0 + tx];
    }
    __syncthreads();
    #pragma unroll
    for (int r = 0; r < 4; ++r) {
        int p = p0 + ty + r * 8;
        int h = p / 56, wcol = p - h * 56;
        xpad[(((size_t)n * 58 + h + 1) * 58 + (wcol + 1)) * 256 + c0 + tx] =
            (__bf16)tile[tx][ty + r * 8];
    }
}

// ---------------------------------------------------------------------------
// Kernel 2b: zero the 1-cell halo of xpad.
// ---------------------------------------------------------------------------
__global__ __launch_bounds__(256) void zero_halo_kernel(__bf16* __restrict__ xpad) {
    const int t = blockIdx.x * 256 + threadIdx.x;
    const int cvec = t & 31;
    const int r    = t >> 5;
    const int n    = r / 228;
    const int pos  = r - n * 228;
    if (n >= 32) return;
    int h, wcol;
    if      (pos < 58)  { h = 0;          wcol = pos; }
    else if (pos < 116) { h = 57;         wcol = pos - 58; }
    else if (pos < 172) { h = pos - 115;  wcol = 0; }
    else                { h = pos - 171;  wcol = 57; }
    i32x4* dst = (i32x4*)(xpad + (((size_t)n * 58 + h) * 58 + wcol) * 256);
    dst[cvec] = (i32x4){0, 0, 0, 0};
}

// ---------------------------------------------------------------------------
// Kernel 3: implicit-GEMM conv. 128o x 128pos tile, 256 thr (4 waves 2Mx2N),
// per-wave 64x64 (2x2 of mfma_32x32x16), BK=64, 36 K-steps.
// LDS: 64 KiB dynamic, double-buffered (A 16K + B 16K per buffer)
//   -> 2 blocks/CU co-resident: co-scheduled blocks hide each other's stalls.
// FIFO-prefix staging (8 issues/step of 4 KB): order [A0..A3,B0,B1][B2,B3];
//   ph0 (n0-half) waits vmcnt(2), ph1 (n1-half) waits vmcnt(6) [tail: 0].
// 16B-chunk XOR swizzle (chunk ^= row&7), pre-applied on the global source
// so the global_load_lds destination stays linear (both-sides rule).
// Grid 1568 = 784 pos-tiles x 2 o-halves; XCD swizzle keeps both o-halves
// of a pos-tile on the same XCD (shared xpad reads in its L2).
// ---------------------------------------------------------------------------
__device__ __forceinline__ void gload_lds16(const void* g, void* l) {
    __builtin_amdgcn_global_load_lds((const __attribute__((address_space(1))) void*)g,
                                     (__attribute__((address_space(3))) void*)l,
                                     16, 0, 0);
}

__global__ __launch_bounds__(256, 2) void conv_mfma_kernel(const __bf16* __restrict__ xpad,
                                                           const __bf16* __restrict__ wq,
                                                           float* __restrict__ out) {
    extern __shared__ __align__(16) char lds[];   // 65536 B
    const int tid  = threadIdx.x;
    const int wv   = tid >> 6;          // 0..3
    const int lane = tid & 63;
    const int bid  = blockIdx.x;
    const int swz  = (bid & 7) * 196 + (bid >> 3);   // 1568 = 8*196 bijection
    const int ptile = swz >> 1;                      // 0..783
    const int ohalf = swz & 1;
    const int p0   = ptile * 128;
    const int o0   = ohalf * 128;

    const int wm = wv >> 1;        // 0..1 : o 64-half within tile
    const int wn = wv & 1;         // 0..1 : pos 64-half within tile

    // ---- staging setup --------------------------------------------------
    const int schunk = (lane & 7) ^ (lane >> 3);     // pre-swizzled source chunk
    // A-issue j: rows j*32 + wv*8 + (lane>>3)   (LDS row r <-> o0 + r)
    const __bf16* pAg = wq + (size_t)(o0 + wv * 8 + (lane >> 3)) * 256 + schunk * 8;
    // B-issue j: rows (wv&1)*64 + (j>>1)*32 + (j&1)*16 + (wv>>1)*8 + (lane>>3)
    const __bf16* pB[4];
    #pragma unroll
    for (int j = 0; j < 4; ++j) {
        int row = (wv & 1) * 64 + (j >> 1) * 32 + (j & 1) * 16 + (wv >> 1) * 8 + (lane >> 3);
        int pos = p0 + row;                          // < 100352 (exact tiling)
        int ni = pos / 3136;
        int hw = pos - ni * 3136;
        int h = hw / 56, w = hw - h * 56;
        pB[j] = xpad + (((size_t)ni * 58 + h) * 58 + w) * 256 + schunk * 8;
    }
    // wave-uniform LDS dest bases (HW adds lane*16). Offsets within a buffer:
    // A at +0 (16 KB), B at +16384 (16 KB).
    const int adst = wv * 1024;                                  // + j*4096
    const int bdst = 16384 + (wv & 1) * 8192 + (wv >> 1) * 1024; // + (j>>1)*4096 + (j&1)*2048

    // ---- fragment read setup (128B rows; stored chunk = c ^ (row&7)) ----
    const int hi = lane >> 5;
    int kxo[4];
    #pragma unroll
    for (int ks = 0; ks < 4; ++ks)
        kxo[ks] = ((ks * 2 + hi) ^ (lane & 7)) * 16;
    const int arowb = (wm * 64 + (lane & 31)) * 128;             // + m*4096
    const int browb = 16384 + (wn * 64 + (lane & 31)) * 128;     // + n*4096

    f32x16 acc[2][2];
    #pragma unroll
    for (int m = 0; m < 2; ++m)
        #pragma unroll
        for (int n = 0; n < 2; ++n)
            acc[m][n] = (f32x16)(0.f);

    // ---- prologue: stage K-step 0 into buf0, canonical FIFO order -------
    {
        char* buf = lds;
        gload_lds16(pAg + 0 * 8192, buf + adst + 0 * 4096);                  // A0
        gload_lds16(pAg + 1 * 8192, buf + adst + 1 * 4096);                  // A1
        gload_lds16(pAg + 2 * 8192, buf + adst + 2 * 4096);                  // A2
        gload_lds16(pAg + 3 * 8192, buf + adst + 3 * 4096);                  // A3
        gload_lds16(pB[0],          buf + bdst + 0 * 4096 + 0 * 2048);       // B0
        gload_lds16(pB[1],          buf + bdst + 0 * 4096 + 1 * 2048);       // B1
        gload_lds16(pB[2],          buf + bdst + 1 * 4096 + 0 * 2048);       // B2
        gload_lds16(pB[3],          buf + bdst + 1 * 4096 + 1 * 2048);       // B3
    }

    for (int s = 0; s < 36; ++s) {
        const char* Rd = lds + ((s & 1) ? 32768 : 0);
        char*       Wr = lds + ((s & 1) ? 0 : 32768);
        const bool stg = (s < 35);
        size_t aoffN = 0, boffN = 0;
        if (stg) {
            const int sn = s + 1;
            const int tapN = sn >> 2, ccN = sn & 3;
            const int khN = tapN / 3, kwN = tapN - khN * 3;
            aoffN = (size_t)tapN * 65536 + ccN * 64;
            boffN = (size_t)(khN * 58 + kwN) * 256 + ccN * 64;
        }

        bf16x8 a0[4], a1[4], b[4];

        // ==== phase 0: (m0,m1) x n0 — needs FIFO prefix 6 [A0..A3,B0,B1] ====
        WAITVM(2);
        BAR();
        #pragma unroll
        for (int ks = 0; ks < 4; ++ks) {
            a0[ks] = *(const bf16x8*)(Rd + arowb + 0 * 4096 + kxo[ks]);
            a1[ks] = *(const bf16x8*)(Rd + arowb + 1 * 4096 + kxo[ks]);
            b[ks]  = *(const bf16x8*)(Rd + browb + 0 * 4096 + kxo[ks]);
        }
        if (stg) {
            gload_lds16(pAg + 0 * 8192 + aoffN, Wr + adst + 0 * 4096);       // A0
            gload_lds16(pAg + 1 * 8192 + aoffN, Wr + adst + 1 * 4096);       // A1
            gload_lds16(pAg + 2 * 8192 + aoffN, Wr + adst + 2 * 4096);       // A2
            gload_lds16(pAg + 3 * 8192 + aoffN, Wr + adst + 3 * 4096);       // A3
            gload_lds16(pB[0] + boffN,          Wr + bdst + 0 * 2048);       // B0
            gload_lds16(pB[1] + boffN,          Wr + bdst + 2048);           // B1
        }
        __builtin_amdgcn_s_setprio(1);
        #pragma unroll
        for (int ks = 0; ks < 4; ++ks) {
            acc[0][0] = __builtin_amdgcn_mfma_f32_32x32x16_bf16(a0[ks], b[ks], acc[0][0], 0, 0, 0);
            acc[1][0] = __builtin_amdgcn_mfma_f32_32x32x16_bf16(a1[ks], b[ks], acc[1][0], 0, 0, 0);
        }
        __builtin_amdgcn_s_setprio(0);

        // ==== phase 1: (m0,m1) x n1 — needs FIFO prefix 8 [+B2,B3] ====
        if (stg) { WAITVM(6); } else { WAITVM(0); }
        BAR();
        #pragma unroll
        for (int ks = 0; ks < 4; ++ks)
            b[ks] = *(const bf16x8*)(Rd + browb + 1 * 4096 + kxo[ks]);
        if (stg) {
            gload_lds16(pB[2] + boffN, Wr + bdst + 4096);                    // B2
            gload_lds16(pB[3] + boffN, Wr + bdst + 4096 + 2048);             // B3
        }
        __builtin_amdgcn_s_setprio(1);
        #pragma unroll
        for (int ks = 0; ks < 4; ++ks) {
            acc[0][1] = __builtin_amdgcn_mfma_f32_32x32x16_bf16(a0[ks], b[ks], acc[0][1], 0, 0, 0);
            acc[1][1] = __builtin_amdgcn_mfma_f32_32x32x16_bf16(a1[ks], b[ks], acc[1][1], 0, 0, 0);
        }
        __builtin_amdgcn_s_setprio(0);
        BAR();
    }

    // ---- epilogue: 32x32 C/D: col(pos)=lane&31, row(o)=(r&3)+8*(r>>2)+4*hi
    #pragma unroll
    for (int n = 0; n < 2; ++n) {
        const int pos = p0 + wn * 64 + n * 32 + (lane & 31);
        const int ni = pos / 3136;
        const int hw = pos - ni * 3136;
        float* ob = out + (size_t)ni * 802816 + hw;
        #pragma unroll
        for (int m = 0; m < 2; ++m) {
            const int om = o0 + wm * 64 + m * 32 + 4 * hi;
            #pragma unroll
            for (int r = 0; r < 16; ++r) {
                const int o = om + (r & 3) + 8 * (r >> 2);
                ob[(size_t)o * 3136] = acc[m][n][r];
            }
        }
    }
}

// ---------------------------------------------------------------------------
// Fallback: naive direct conv (only if ws_size too small).
// ---------------------------------------------------------------------------
__global__ __launch_bounds__(256) void conv_naive_kernel(const float* __restrict__ x,
                                                         const float* __restrict__ w,
                                                         float* __restrict__ out) {
    const int n = blockIdx.z;
    const int o = blockIdx.y;
    const int strip = blockIdx.x;
    __shared__ float wqs[2304];
    __shared__ float red[4];
    __shared__ float s_scale;
    const float* wo = w + (size_t)o * 2304;
    float m = 0.f;
    for (int i = threadIdx.x; i < 2304; i += 256) m = fmaxf(m, fabsf(wo[i]));
    #pragma unroll
    for (int off = 32; off >= 1; off >>= 1) m = fmaxf(m, __shfl_down(m, off));
    if ((threadIdx.x & 63) == 0) red[threadIdx.x >> 6] = m;
    __syncthreads();
    if (threadIdx.x == 0) {
        float am = fmaxf(fmaxf(red[0], red[1]), fmaxf(red[2], red[3]));
        s_scale = fmaxf(am / QMAX, SCALE_MIN);
    }
    __syncthreads();
    const float scale = s_scale;
    for (int i = threadIdx.x; i < 2304; i += 256) {
        float q = rintf(wo[i] / scale);
        q = fminf(QMAX, fmaxf(-QMAX, q));
        wqs[i] = q * scale;
    }
    __syncthreads();
    int p = strip * 256 + threadIdx.x;
    if (p >= 3136) return;
    int h = p / 56, wcol = p - h * 56;
    float acc = 0.f;
    for (int c = 0; c < 256; ++c) {
        const float* xc = x + ((size_t)(n * 256 + c)) * 3136;
        const float* wk = wqs + c * 9;
        #pragma unroll
        for (int kh = 0; kh < 3; ++kh) {
            int hh = h + kh - 1;
            if (hh < 0 || hh > 55) continue;
            #pragma unroll
            for (int kw = 0; kw < 3; ++kw) {
                int ww2 = wcol + kw - 1;
                if (ww2 < 0 || ww2 > 55) continue;
                acc += xc[hh * 56 + ww2] * wk[kh * 3 + kw];
            }
        }
    }
    out[((size_t)(n * 256 + o)) * 3136 + p] = acc;
}

// ---------------------------------------------------------------------------
extern "C" void kernel_launch(void* const* d_in, const int* in_sizes, int n_in,
                              void* d_out, int out_size, void* d_ws, size_t ws_size,
                              hipStream_t stream) {
    const float* x = (const float*)d_in[0];
    const float* w = (const float*)d_in[1];
    float* out = (float*)d_out;

    const size_t WQ_BYTES   = 9ull * 256 * 256 * 2;            // 1,179,648
    const size_t XPAD_OFF   = WQ_BYTES;
    const size_t XPAD_BYTES = 32ull * 58 * 58 * 256 * 2;       // 55,083,008

    if (ws_size >= XPAD_OFF + XPAD_BYTES) {
        __bf16* wq   = (__bf16*)d_ws;
        __bf16* xpad = (__bf16*)((char*)d_ws + XPAD_OFF);
        hipFuncSetAttribute((const void*)conv_mfma_kernel,
                            hipFuncAttributeMaxDynamicSharedMemorySize, 65536);
        zero_halo_kernel<<<912, 256, 0, stream>>>(xpad);
        quant_w_kernel<<<256, 256, 0, stream>>>(w, wq);
        convert_x_kernel<<<dim3(98, 8, 32), 256, 0, stream>>>(x, xpad);
        conv_mfma_kernel<<<1568, 256, 65536, stream>>>(xpad, wq, out);
    } else {
        conv_naive_kernel<<<dim3(13, 256, 32), 256, 0, stream>>>(x, w, out);
    }
}